// Round 1
// baseline (265.842 us; speedup 1.0000x reference)
//
#include <hip/hip_runtime.h>
#include <hip/hip_bf16.h>
#include <stdint.h>

// ---------- types ----------
typedef __attribute__((ext_vector_type(8))) __bf16 bf16x8;
typedef __attribute__((ext_vector_type(4))) float  f32x4;

#define BATCH  2
#define SEQ    2048
#define DMODEL 1024
#define NHEAD  16
#define HDIM   64
#define MTOT   (BATCH * SEQ)   // 4096

// async global->LDS, 16B per lane. LDS dest must be wave-uniform base + lane*16.
__device__ __forceinline__ void gload_lds16(const void* g, void* l) {
  __builtin_amdgcn_global_load_lds(
      (const __attribute__((address_space(1))) unsigned int*)g,
      (__attribute__((address_space(3))) unsigned int*)(uintptr_t)l,
      16, 0, 0);
}

// ---------- fp32 -> bf16 cast ----------
__global__ void cast_kernel(const float* __restrict__ in, __bf16* __restrict__ out, int n) {
  int i = blockIdx.x * blockDim.x + threadIdx.x;
  int stride = gridDim.x * blockDim.x;
  for (; i < n; i += stride) out[i] = (__bf16)in[i];
}

// ---------- GEMM: C[M,N] = A[M,K] * W[N,K]^T  (bf16 in, fp32 acc) ----------
// WMODE 0: bf16 out (W/out selected by blockIdx.z among 3)
// WMODE 1: fp32 out + bias
template <int WMODE>
__global__ __launch_bounds__(256)
void gemm_bt(const __bf16* __restrict__ A,
             const __bf16* __restrict__ W0, const __bf16* __restrict__ W1,
             const __bf16* __restrict__ W2,
             __bf16* __restrict__ O0, __bf16* __restrict__ O1, __bf16* __restrict__ O2,
             float* __restrict__ OF, const float* __restrict__ bias,
             int M, int N, int K)
{
  const __bf16* W  = (blockIdx.z == 0) ? W0 : (blockIdx.z == 1 ? W1 : W2);
  __bf16*       Ob = (blockIdx.z == 0) ? O0 : (blockIdx.z == 1 ? O1 : O2);

  __shared__ __align__(16) __bf16 As[128 * 32];
  __shared__ __align__(16) __bf16 Bs[128 * 32];

  const int tid  = threadIdx.x;
  const int wave = tid >> 6;
  const int lane = tid & 63;
  const int wr = wave >> 1, wc = wave & 1;   // 2x2 wave grid, each wave 64x64
  const int fr = lane & 15, fq = lane >> 4;
  const int bm = blockIdx.x, bn = blockIdx.y;

  f32x4 acc[4][4] = {};

  // staging chunk mapping: chunk c (0..511) = 16B; row = c>>2, col8 = (c&3)*8
  const int c0 = tid, c1 = tid + 256;
  const __bf16* gA0 = A + (size_t)(bm * 128 + (c0 >> 2)) * K + (c0 & 3) * 8;
  const __bf16* gA1 = A + (size_t)(bm * 128 + (c1 >> 2)) * K + (c1 & 3) * 8;
  const __bf16* gB0 = W + (size_t)(bn * 128 + (c0 >> 2)) * K + (c0 & 3) * 8;
  const __bf16* gB1 = W + (size_t)(bn * 128 + (c1 >> 2)) * K + (c1 & 3) * 8;

  for (int k0 = 0; k0 < K; k0 += 32) {
    gload_lds16(gA0 + k0, As + c0 * 8);
    gload_lds16(gB0 + k0, Bs + c0 * 8);
    gload_lds16(gA1 + k0, As + c1 * 8);
    gload_lds16(gB1 + k0, Bs + c1 * 8);
    __syncthreads();   // compiler emits vmcnt(0) drain before barrier

    bf16x8 a[4], b[4];
#pragma unroll
    for (int m = 0; m < 4; ++m)
      a[m] = *(const bf16x8*)(As + (wr * 64 + m * 16 + fr) * 32 + fq * 8);
#pragma unroll
    for (int n = 0; n < 4; ++n)
      b[n] = *(const bf16x8*)(Bs + (wc * 64 + n * 16 + fr) * 32 + fq * 8);
#pragma unroll
    for (int m = 0; m < 4; ++m)
#pragma unroll
      for (int n = 0; n < 4; ++n)
        acc[m][n] = __builtin_amdgcn_mfma_f32_16x16x32_bf16(a[m], b[n], acc[m][n], 0, 0, 0);
    __syncthreads();
  }

  // epilogue: C/D layout col = lane&15, row = (lane>>4)*4 + j   [m89-verified]
#pragma unroll
  for (int m = 0; m < 4; ++m) {
#pragma unroll
    for (int n = 0; n < 4; ++n) {
      const int col = bn * 128 + wc * 64 + n * 16 + fr;
#pragma unroll
      for (int j = 0; j < 4; ++j) {
        const int row = bm * 128 + wr * 64 + m * 16 + fq * 4 + j;
        float v = acc[m][n][j];
        if constexpr (WMODE == 1) {
          OF[(size_t)row * N + col] = v + bias[col];
        } else {
          Ob[(size_t)row * N + col] = (__bf16)v;
        }
      }
    }
  }
}

// ---------- flash attention (causal), per (b,h), 64 q-rows per block ----------
__global__ __launch_bounds__(256)
void attn_kernel(const __bf16* __restrict__ Q, const __bf16* __restrict__ Km,
                 const __bf16* __restrict__ Vm, __bf16* __restrict__ O)
{
  const int D = DMODEL;
  const int bh = blockIdx.y;           // 0..31
  const int b = bh >> 4, h = bh & 15;
  const int q0 = blockIdx.x * 64;
  const int tid = threadIdx.x, wave = tid >> 6, lane = tid & 63;
  const int fr = lane & 15, fq = lane >> 4;

  const size_t base = (size_t)b * SEQ * D + (size_t)h * HDIM;
  const __bf16* Qb = Q  + base;
  const __bf16* Kb = Km + base;
  const __bf16* Vb = Vm + base;
  __bf16*       Ob = O  + base;

  __shared__ __align__(16) __bf16 Vt[64][72];      // V^T tile: Vt[d][kk], padded
  __shared__ __align__(16) __bf16 Pl[4][16][72];   // per-wave P, padded

  // Q fragments: wave handles q-rows [q0 + wave*16, +16)
  bf16x8 qf[2];
#pragma unroll
  for (int kc = 0; kc < 2; ++kc)
    qf[kc] = *(const bf16x8*)(Qb + (size_t)(q0 + wave * 16 + fr) * D + kc * 32 + fq * 8);

  f32x4 ctx[4] = {};
  float m_run[4], l_run[4];
#pragma unroll
  for (int j = 0; j < 4; ++j) { m_run[j] = -1e30f; l_run[j] = 0.f; }

  const int ntiles = blockIdx.x + 1;   // kv tiles of 64 up to diagonal
  for (int kt = 0; kt < ntiles; ++kt) {
    const int kv0 = kt * 64;

    // stage V transposed: thread c reads V[kv0 + c/8][(c%8)*8 .. +8]
#pragma unroll
    for (int half = 0; half < 2; ++half) {
      int c = tid + half * 256;
      int kk = c >> 3, d0 = (c & 7) * 8;
      bf16x8 v = *(const bf16x8*)(Vb + (size_t)(kv0 + kk) * D + d0);
#pragma unroll
      for (int j = 0; j < 8; ++j) Vt[d0 + j][kk] = v[j];
    }
    __syncthreads();

    // S = Q K^T / 8 with causal mask; K fragments straight from global (L2-hot)
    float sv[4][4];   // [ki][j]
#pragma unroll
    for (int ki = 0; ki < 4; ++ki) {
      f32x4 s = {};
#pragma unroll
      for (int kc = 0; kc < 2; ++kc) {
        bf16x8 kf = *(const bf16x8*)(Kb + (size_t)(kv0 + ki * 16 + fr) * D + kc * 32 + fq * 8);
        s = __builtin_amdgcn_mfma_f32_16x16x32_bf16(qf[kc], kf, s, 0, 0, 0);
      }
      const int kcol = kv0 + ki * 16 + fr;
#pragma unroll
      for (int j = 0; j < 4; ++j) {
        const int qrow = q0 + wave * 16 + fq * 4 + j;
        sv[ki][j] = (kcol <= qrow) ? s[j] * 0.125f : -1e30f;
      }
    }

    // online softmax (rows live in 16-lane groups sharing fq)
    float mnew[4], scl[4], rsum[4];
#pragma unroll
    for (int j = 0; j < 4; ++j) {
      float r = fmaxf(fmaxf(sv[0][j], sv[1][j]), fmaxf(sv[2][j], sv[3][j]));
#pragma unroll
      for (int off = 1; off < 16; off <<= 1) r = fmaxf(r, __shfl_xor(r, off, 64));
      mnew[j] = fmaxf(m_run[j], r);
      scl[j]  = __expf(m_run[j] - mnew[j]);
      rsum[j] = 0.f;
    }
#pragma unroll
    for (int ki = 0; ki < 4; ++ki)
#pragma unroll
      for (int j = 0; j < 4; ++j) {
        float p = __expf(sv[ki][j] - mnew[j]);
        sv[ki][j] = p;
        rsum[j] += p;
      }
#pragma unroll
    for (int j = 0; j < 4; ++j) {
#pragma unroll
      for (int off = 1; off < 16; off <<= 1) rsum[j] += __shfl_xor(rsum[j], off, 64);
      l_run[j] = l_run[j] * scl[j] + rsum[j];
      m_run[j] = mnew[j];
    }

    // P -> LDS (bf16) to re-layout into MFMA A fragment
#pragma unroll
    for (int ki = 0; ki < 4; ++ki)
#pragma unroll
      for (int j = 0; j < 4; ++j)
        Pl[wave][fq * 4 + j][ki * 16 + fr] = (__bf16)sv[ki][j];

    // rescale ctx accumulator
#pragma unroll
    for (int dt = 0; dt < 4; ++dt)
#pragma unroll
      for (int j = 0; j < 4; ++j) ctx[dt][j] *= scl[j];

    // PV: ctx += P * V   (A = P from LDS, B = V^T from Vt)
    bf16x8 pa[2];
#pragma unroll
    for (int kc = 0; kc < 2; ++kc)
      pa[kc] = *(const bf16x8*)(&Pl[wave][fr][kc * 32 + fq * 8]);
#pragma unroll
    for (int dt = 0; dt < 4; ++dt) {
#pragma unroll
      for (int kc = 0; kc < 2; ++kc) {
        bf16x8 vf = *(const bf16x8*)(&Vt[dt * 16 + fr][kc * 32 + fq * 8]);
        ctx[dt] = __builtin_amdgcn_mfma_f32_16x16x32_bf16(pa[kc], vf, ctx[dt], 0, 0, 0);
      }
    }
    __syncthreads();   // protect Vt before next tile overwrites
  }

  // write ctx / l  (bf16) to [b*2048+row][h*64+col]
#pragma unroll
  for (int dt = 0; dt < 4; ++dt)
#pragma unroll
    for (int j = 0; j < 4; ++j) {
      const int row = q0 + wave * 16 + fq * 4 + j;
      const int col = dt * 16 + fr;
      Ob[(size_t)row * D + col] = (__bf16)(ctx[dt][j] / l_run[j]);
    }
}

// ---------- launch ----------
extern "C" void kernel_launch(void* const* d_in, const int* in_sizes, int n_in,
                              void* d_out, int out_size, void* d_ws, size_t ws_size,
                              hipStream_t stream) {
  (void)in_sizes; (void)n_in; (void)out_size; (void)ws_size;
  const float* x  = (const float*)d_in[0];
  const float* Wq = (const float*)d_in[1];
  const float* Wk = (const float*)d_in[2];
  const float* Wv = (const float*)d_in[3];
  const float* Wo = (const float*)d_in[4];
  const float* bo = (const float*)d_in[5];
  float* out = (float*)d_out;

  __bf16* ws  = (__bf16*)d_ws;
  __bf16* xb  = ws;                                   // 4M elems
  __bf16* Wqb = xb  + (size_t)MTOT * DMODEL;          // 1M each
  __bf16* Wkb = Wqb + (size_t)DMODEL * DMODEL;
  __bf16* Wvb = Wkb + (size_t)DMODEL * DMODEL;
  __bf16* Wob = Wvb + (size_t)DMODEL * DMODEL;
  __bf16* Qb  = Wob + (size_t)DMODEL * DMODEL;        // 4M each
  __bf16* Kb  = Qb  + (size_t)MTOT * DMODEL;
  __bf16* Vb  = Kb  + (size_t)MTOT * DMODEL;
  __bf16* ctxb = xb;  // reuse: x is dead after QKV projections

  cast_kernel<<<2048, 256, 0, stream>>>(x,  xb,  MTOT * DMODEL);
  cast_kernel<<<256,  256, 0, stream>>>(Wq, Wqb, DMODEL * DMODEL);
  cast_kernel<<<256,  256, 0, stream>>>(Wk, Wkb, DMODEL * DMODEL);
  cast_kernel<<<256,  256, 0, stream>>>(Wv, Wvb, DMODEL * DMODEL);
  cast_kernel<<<256,  256, 0, stream>>>(Wo, Wob, DMODEL * DMODEL);

  gemm_bt<0><<<dim3(32, 8, 3), 256, 0, stream>>>(
      xb, Wqb, Wkb, Wvb, Qb, Kb, Vb, nullptr, nullptr, MTOT, DMODEL, DMODEL);

  attn_kernel<<<dim3(32, 32), 256, 0, stream>>>(Qb, Kb, Vb, ctxb);

  gemm_bt<1><<<dim3(32, 8, 1), 256, 0, stream>>>(
      ctxb, Wob, Wob, Wob, nullptr, nullptr, nullptr, out, bo, MTOT, DMODEL, DMODEL);
}

// Round 2
// 151.922 us; speedup vs baseline: 1.7499x; 1.7499x over previous
//
#include <hip/hip_runtime.h>
#include <hip/hip_bf16.h>
#include <stdint.h>

typedef __attribute__((ext_vector_type(8)))  __bf16   bf16x8;
typedef __attribute__((ext_vector_type(4)))  float    f32x4;
typedef __attribute__((ext_vector_type(16))) float    f32x16;
typedef __attribute__((ext_vector_type(4)))  unsigned u32x4;
typedef __attribute__((ext_vector_type(2)))  unsigned u32x2;

#define BATCH  2
#define SEQ    2048
#define DMODEL 1024
#define NHEAD  16
#define HDIM   64
#define MTOT   (BATCH * SEQ)   // 4096

// async global->LDS, 16B per lane (dest = wave-uniform base + lane*16)
__device__ __forceinline__ void gload_lds16(const void* g, void* l) {
  __builtin_amdgcn_global_load_lds(
      (const __attribute__((address_space(1))) unsigned int*)g,
      (__attribute__((address_space(3))) unsigned int*)(uintptr_t)l,
      16, 0, 0);
}

// pack two f32 -> one dword of 2 bf16 (compiler emits v_cvt_pk_bf16_f32)
__device__ __forceinline__ unsigned pkbf(float a, float b) {
  unsigned lo = (unsigned)__builtin_bit_cast(unsigned short, (__bf16)a);
  unsigned hb = (unsigned)__builtin_bit_cast(unsigned short, (__bf16)b);
  return lo | (hb << 16);
}

// ---------- fp32 -> bf16 cast ----------
__global__ void cast_kernel(const float* __restrict__ in, __bf16* __restrict__ out, int n) {
  int i = blockIdx.x * blockDim.x + threadIdx.x;
  int stride = gridDim.x * blockDim.x;
  for (; i < n; i += stride) out[i] = (__bf16)in[i];
}

// ---------- shared 128x128 GEMM mainloop: acc = A[128,K] * W[128,K]^T ----------
__device__ __forceinline__ void gemm_tile_128(const __bf16* __restrict__ A,
                                              const __bf16* __restrict__ W,
                                              int bm, int bn, int Kd,
                                              f32x4 (&acc)[4][4])
{
  __shared__ __align__(16) __bf16 As[128 * 32];
  __shared__ __align__(16) __bf16 Bs[128 * 32];
  const int tid  = threadIdx.x;
  const int wave = tid >> 6, lane = tid & 63;
  const int wr = wave >> 1, wc = wave & 1;
  const int fr = lane & 15, fq = lane >> 4;
  const int c0 = tid, c1 = tid + 256;
  const __bf16* gA0 = A + (size_t)(bm * 128 + (c0 >> 2)) * Kd + (c0 & 3) * 8;
  const __bf16* gA1 = A + (size_t)(bm * 128 + (c1 >> 2)) * Kd + (c1 & 3) * 8;
  const __bf16* gB0 = W + (size_t)(bn * 128 + (c0 >> 2)) * Kd + (c0 & 3) * 8;
  const __bf16* gB1 = W + (size_t)(bn * 128 + (c1 >> 2)) * Kd + (c1 & 3) * 8;

  for (int k0 = 0; k0 < Kd; k0 += 32) {
    gload_lds16(gA0 + k0, As + c0 * 8);
    gload_lds16(gB0 + k0, Bs + c0 * 8);
    gload_lds16(gA1 + k0, As + c1 * 8);
    gload_lds16(gB1 + k0, Bs + c1 * 8);
    __syncthreads();
    bf16x8 a[4], b[4];
#pragma unroll
    for (int m = 0; m < 4; ++m)
      a[m] = *(const bf16x8*)(As + (wr * 64 + m * 16 + fr) * 32 + fq * 8);
#pragma unroll
    for (int n = 0; n < 4; ++n)
      b[n] = *(const bf16x8*)(Bs + (wc * 64 + n * 16 + fr) * 32 + fq * 8);
#pragma unroll
    for (int m = 0; m < 4; ++m)
#pragma unroll
      for (int n = 0; n < 4; ++n)
        acc[m][n] = __builtin_amdgcn_mfma_f32_16x16x32_bf16(a[m], b[n], acc[m][n], 0, 0, 0);
    __syncthreads();
  }
}

// ---------- QKV projections (z=0: Q*scale, z=1: K, z=2: VT = Wv * x^T) ----------
__global__ __launch_bounds__(256)
void gemm_qkv(const __bf16* __restrict__ xb,
              const __bf16* __restrict__ Wq, const __bf16* __restrict__ Wk,
              const __bf16* __restrict__ Wv,
              __bf16* __restrict__ Qo, __bf16* __restrict__ Ko, __bf16* __restrict__ VTo,
              float qscale)
{
  const int z = blockIdx.z;
  const __bf16* A; const __bf16* W; __bf16* Ob; float scale; int bm, bn, Nn;
  if (z == 2)      { A = Wv; W = xb; Ob = VTo; scale = 1.f;    bm = blockIdx.y; bn = blockIdx.x; Nn = MTOT;   }
  else if (z == 1) { A = xb; W = Wk; Ob = Ko;  scale = 1.f;    bm = blockIdx.x; bn = blockIdx.y; Nn = DMODEL; }
  else             { A = xb; W = Wq; Ob = Qo;  scale = qscale; bm = blockIdx.x; bn = blockIdx.y; Nn = DMODEL; }

  f32x4 acc[4][4] = {};
  gemm_tile_128(A, W, bm, bn, DMODEL, acc);

  const int lane = threadIdx.x & 63, wave = threadIdx.x >> 6;
  const int wr = wave >> 1, wc = wave & 1;
  const int fr = lane & 15, fq = lane >> 4;
#pragma unroll
  for (int m = 0; m < 4; ++m)
#pragma unroll
    for (int n = 0; n < 4; ++n) {
      const int col = bn * 128 + wc * 64 + n * 16 + fr;
#pragma unroll
      for (int j = 0; j < 4; ++j) {
        const int row = bm * 128 + wr * 64 + m * 16 + fq * 4 + j;
        Ob[(size_t)row * Nn + col] = (__bf16)(acc[m][n][j] * scale);
      }
    }
}

// ---------- output projection: out = ctx * Wo^T + b ----------
__global__ __launch_bounds__(256)
void gemm_out(const __bf16* __restrict__ A, const __bf16* __restrict__ W,
              float* __restrict__ OF, const float* __restrict__ bias)
{
  f32x4 acc[4][4] = {};
  gemm_tile_128(A, W, blockIdx.x, blockIdx.y, DMODEL, acc);

  const int lane = threadIdx.x & 63, wave = threadIdx.x >> 6;
  const int wr = wave >> 1, wc = wave & 1;
  const int fr = lane & 15, fq = lane >> 4;
#pragma unroll
  for (int m = 0; m < 4; ++m)
#pragma unroll
    for (int n = 0; n < 4; ++n) {
      const int col = blockIdx.y * 128 + wc * 64 + n * 16 + fr;
#pragma unroll
      for (int j = 0; j < 4; ++j) {
        const int row = blockIdx.x * 128 + wr * 64 + m * 16 + fq * 4 + j;
        OF[(size_t)row * DMODEL + col] = acc[m][n][j] + bias[col];
      }
    }
}

// ---------- flash attention: 1 wave = one 32-row q-tile, no LDS, no barriers ----------
// Swapped QK^T via 32x32x16 MFMA: S^T[kv][q], q = lane&31 per lane.
// C/D layout (m74/m101): col=lane&31, row=(r&3)+8*(r>>2)+4*(lane>>5).
__global__ __launch_bounds__(256, 2)
void attn_kernel(const __bf16* __restrict__ Qg, const __bf16* __restrict__ Kg,
                 const __bf16* __restrict__ VTg, __bf16* __restrict__ Og)
{
  const int tid = threadIdx.x;
  const int wv  = tid >> 6, lane = tid & 63;
  const int ln  = lane & 31, hi = lane >> 5;
  const int x   = blockIdx.x;          // 0..15
  const int bh  = blockIdx.y;          // 0..31
  const int b   = bh >> 4, h = bh & 15;

  // balanced quartile set {x, 31-x, 32+x, 63-x}, rotated per block for SIMD balance
  const int sel = (wv + x) & 3;
  const int qt  = (sel == 0) ? x : (sel == 1) ? (31 - x) : (sel == 2) ? (32 + x) : (63 - x);
  const int q0w = qt * 32;

  const __bf16* Qp = Qg + ((size_t)b * SEQ + q0w + ln) * DMODEL + h * HDIM + hi * 8;
  const __bf16* Kp = Kg + ((size_t)b * SEQ) * DMODEL + h * HDIM + hi * 8;
  const __bf16* Vp = VTg + (size_t)(h * HDIM) * MTOT + (size_t)b * SEQ + hi * 8;
  __bf16*       Op = Og + ((size_t)b * SEQ + q0w + ln) * DMODEL + h * HDIM;

  // Q fragments (B-operand): q=ln, k = kc*16 + hi*8 + j   (Q pre-scaled by 0.125*log2e)
  bf16x8 qf[4];
#pragma unroll
  for (int kc = 0; kc < 4; ++kc)
    qf[kc] = *(const bf16x8*)(Qp + kc * 16);

  f32x16 ctx0 = {}, ctx1 = {};
  float m_run = -1e30f, l_run = 0.f;

  const int ntiles = (q0w >> 6) + 1;
  for (int t = 0; t < ntiles; ++t) {
    const int kv0 = t * 64;

    // --- S^T = K * Q^T  (two 32-kv blocks) ---
    f32x16 sv0 = {}, sv1 = {};
#pragma unroll
    for (int kc = 0; kc < 4; ++kc) {
      bf16x8 kf = *(const bf16x8*)(Kp + (size_t)(kv0 + ln) * DMODEL + kc * 16);
      sv0 = __builtin_amdgcn_mfma_f32_32x32x16_bf16(kf, qf[kc], sv0, 0, 0, 0);
    }
#pragma unroll
    for (int kc = 0; kc < 4; ++kc) {
      bf16x8 kf = *(const bf16x8*)(Kp + (size_t)(kv0 + 32 + ln) * DMODEL + kc * 16);
      sv1 = __builtin_amdgcn_mfma_f32_32x32x16_bf16(kf, qf[kc], sv1, 0, 0, 0);
    }

    // --- issue V^T loads early (A-operand: d = db*32+ln, k = kv) ---
    bf16x8 vt0[4], vt1[4];
#pragma unroll
    for (int kc = 0; kc < 4; ++kc) {
      vt0[kc] = *(const bf16x8*)(Vp + (size_t)ln * MTOT + kv0 + kc * 16);
      vt1[kc] = *(const bf16x8*)(Vp + (size_t)(32 + ln) * MTOT + kv0 + kc * 16);
    }

    // --- causal mask (only the diagonal tile) ---
    if (t == ntiles - 1) {
      const int qg = q0w + ln;
#pragma unroll
      for (int r = 0; r < 16; ++r) {
        const int kvo = kv0 + (r & 3) + 8 * (r >> 2) + 4 * hi;
        if (kvo > qg)      sv0[r] = -1e30f;
        if (kvo + 32 > qg) sv1[r] = -1e30f;
      }
    }

    // --- online softmax (base-2), per-lane scalar state ---
    float t8[8];
#pragma unroll
    for (int r = 0; r < 8; ++r)
      t8[r] = fmaxf(fmaxf(sv0[r], sv0[r + 8]), fmaxf(sv1[r], sv1[r + 8]));
#pragma unroll
    for (int r = 0; r < 4; ++r) t8[r] = fmaxf(t8[r], t8[r + 4]);
    float mx = fmaxf(fmaxf(t8[0], t8[1]), fmaxf(t8[2], t8[3]));
    mx = fmaxf(mx, __shfl_xor(mx, 32, 64));

    const float mnew = fmaxf(m_run, mx);
    const float scl  = __builtin_amdgcn_exp2f(m_run - mnew);
#pragma unroll
    for (int r = 0; r < 16; ++r) {
      sv0[r] = __builtin_amdgcn_exp2f(sv0[r] - mnew);
      sv1[r] = __builtin_amdgcn_exp2f(sv1[r] - mnew);
    }
    float s8[8];
#pragma unroll
    for (int r = 0; r < 8; ++r)
      s8[r] = (sv0[r] + sv0[r + 8]) + (sv1[r] + sv1[r + 8]);
#pragma unroll
    for (int r = 0; r < 4; ++r) s8[r] += s8[r + 4];
    float sum = (s8[0] + s8[1]) + (s8[2] + s8[3]);
    sum += __shfl_xor(sum, 32, 64);
    l_run = l_run * scl + sum;
    m_run = mnew;
#pragma unroll
    for (int r = 0; r < 16; ++r) { ctx0[r] *= scl; ctx1[r] *= scl; }

    // --- pack P into PV B-fragments (half-exchange via shfl_xor 32) ---
    bf16x8 pf[4];
#pragma unroll
    for (int half = 0; half < 2; ++half) {
      const int r0 = half * 8;
      {
        unsigned pk01 = pkbf(sv0[r0 + 0], sv0[r0 + 1]);
        unsigned pk23 = pkbf(sv0[r0 + 2], sv0[r0 + 3]);
        unsigned pk45 = pkbf(sv0[r0 + 4], sv0[r0 + 5]);
        unsigned pk67 = pkbf(sv0[r0 + 6], sv0[r0 + 7]);
        unsigned x01 = (unsigned)__shfl_xor((int)pk01, 32, 64);
        unsigned x23 = (unsigned)__shfl_xor((int)pk23, 32, 64);
        unsigned x45 = (unsigned)__shfl_xor((int)pk45, 32, 64);
        unsigned x67 = (unsigned)__shfl_xor((int)pk67, 32, 64);
        u32x4 uw = { hi ? x45 : pk01, hi ? x67 : pk23,
                     hi ? pk45 : x01, hi ? pk67 : x23 };
        pf[half] = __builtin_bit_cast(bf16x8, uw);
      }
      {
        unsigned pk01 = pkbf(sv1[r0 + 0], sv1[r0 + 1]);
        unsigned pk23 = pkbf(sv1[r0 + 2], sv1[r0 + 3]);
        unsigned pk45 = pkbf(sv1[r0 + 4], sv1[r0 + 5]);
        unsigned pk67 = pkbf(sv1[r0 + 6], sv1[r0 + 7]);
        unsigned x01 = (unsigned)__shfl_xor((int)pk01, 32, 64);
        unsigned x23 = (unsigned)__shfl_xor((int)pk23, 32, 64);
        unsigned x45 = (unsigned)__shfl_xor((int)pk45, 32, 64);
        unsigned x67 = (unsigned)__shfl_xor((int)pk67, 32, 64);
        u32x4 uw = { hi ? x45 : pk01, hi ? x67 : pk23,
                     hi ? pk45 : x01, hi ? pk67 : x23 };
        pf[2 + half] = __builtin_bit_cast(bf16x8, uw);
      }
    }

    // --- PV: ctx^T[d][q] += V^T-frag * P-frag ---
#pragma unroll
    for (int kc = 0; kc < 4; ++kc)
      ctx0 = __builtin_amdgcn_mfma_f32_32x32x16_bf16(vt0[kc], pf[kc], ctx0, 0, 0, 0);
#pragma unroll
    for (int kc = 0; kc < 4; ++kc)
      ctx1 = __builtin_amdgcn_mfma_f32_32x32x16_bf16(vt1[kc], pf[kc], ctx1, 0, 0, 0);
  }

  // --- epilogue: divide by l, write bf16 (4 consecutive d per 8B store) ---
  const float inv = 1.0f / l_run;
#pragma unroll
  for (int rq = 0; rq < 4; ++rq) {
    u32x2 w0, w1;
    w0.x = pkbf(ctx0[rq * 4 + 0] * inv, ctx0[rq * 4 + 1] * inv);
    w0.y = pkbf(ctx0[rq * 4 + 2] * inv, ctx0[rq * 4 + 3] * inv);
    *(u32x2*)(Op + rq * 8 + hi * 4) = w0;
    w1.x = pkbf(ctx1[rq * 4 + 0] * inv, ctx1[rq * 4 + 1] * inv);
    w1.y = pkbf(ctx1[rq * 4 + 2] * inv, ctx1[rq * 4 + 3] * inv);
    *(u32x2*)(Op + 32 + rq * 8 + hi * 4) = w1;
  }
}

// ---------- launch ----------
extern "C" void kernel_launch(void* const* d_in, const int* in_sizes, int n_in,
                              void* d_out, int out_size, void* d_ws, size_t ws_size,
                              hipStream_t stream) {
  (void)in_sizes; (void)n_in; (void)out_size; (void)ws_size;
  const float* x  = (const float*)d_in[0];
  const float* Wq = (const float*)d_in[1];
  const float* Wk = (const float*)d_in[2];
  const float* Wv = (const float*)d_in[3];
  const float* Wo = (const float*)d_in[4];
  const float* bo = (const float*)d_in[5];
  float* out = (float*)d_out;

  __bf16* ws  = (__bf16*)d_ws;
  __bf16* xb  = ws;                                   // 4M elems
  __bf16* Wqb = xb  + (size_t)MTOT * DMODEL;
  __bf16* Wkb = Wqb + (size_t)DMODEL * DMODEL;
  __bf16* Wvb = Wkb + (size_t)DMODEL * DMODEL;
  __bf16* Wob = Wvb + (size_t)DMODEL * DMODEL;
  __bf16* Qb  = Wob + (size_t)DMODEL * DMODEL;        // 4M
  __bf16* Kb  = Qb  + (size_t)MTOT * DMODEL;          // 4M
  __bf16* VTb = Kb  + (size_t)MTOT * DMODEL;          // 4M, layout [1024][4096]
  __bf16* ctxb = xb;  // reuse: x is dead after QKV projections

  cast_kernel<<<2048, 256, 0, stream>>>(x,  xb,  MTOT * DMODEL);
  cast_kernel<<<256,  256, 0, stream>>>(Wq, Wqb, DMODEL * DMODEL);
  cast_kernel<<<256,  256, 0, stream>>>(Wk, Wkb, DMODEL * DMODEL);
  cast_kernel<<<256,  256, 0, stream>>>(Wv, Wvb, DMODEL * DMODEL);
  cast_kernel<<<256,  256, 0, stream>>>(Wo, Wob, DMODEL * DMODEL);

  // scale = 1/sqrt(64) * log2(e), folded into Q so softmax uses exp2
  const float qscale = 0.125f * 1.4426950408889634f;
  gemm_qkv<<<dim3(32, 8, 3), 256, 0, stream>>>(xb, Wqb, Wkb, Wvb, Qb, Kb, VTb, qscale);

  attn_kernel<<<dim3(16, 32), 256, 0, stream>>>(Qb, Kb, VTb, ctxb);

  gemm_out<<<dim3(32, 8), 256, 0, stream>>>(ctxb, Wob, out, bo);
}

// Round 3
// 130.040 us; speedup vs baseline: 2.0443x; 1.1683x over previous
//
#include <hip/hip_runtime.h>
#include <hip/hip_bf16.h>
#include <stdint.h>

typedef __attribute__((ext_vector_type(8)))  __bf16   bf16x8;
typedef __attribute__((ext_vector_type(4)))  float    f32x4;
typedef __attribute__((ext_vector_type(16))) float    f32x16;
typedef __attribute__((ext_vector_type(4)))  unsigned u32x4;
typedef __attribute__((ext_vector_type(2)))  unsigned u32x2;

#define BATCH  2
#define SEQ    2048
#define DMODEL 1024
#define NHEAD  16
#define HDIM   64
#define MTOT   (BATCH * SEQ)   // 4096

// async global->LDS, 16B per lane (dest = wave-uniform base + lane*16)
__device__ __forceinline__ void gload_lds16(const void* g, void* l) {
  __builtin_amdgcn_global_load_lds(
      (const __attribute__((address_space(1))) unsigned int*)g,
      (__attribute__((address_space(3))) unsigned int*)(uintptr_t)l,
      16, 0, 0);
}

// pack two f32 -> one dword of 2 bf16 (compiler emits v_cvt_pk_bf16_f32)
__device__ __forceinline__ unsigned pkbf(float a, float b) {
  unsigned lo = (unsigned)__builtin_bit_cast(unsigned short, (__bf16)a);
  unsigned hb = (unsigned)__builtin_bit_cast(unsigned short, (__bf16)b);
  return lo | (hb << 16);
}

// ---------- fused fp32 -> bf16 casts (all 5 tensors, one launch) ----------
__global__ void cast_all(const float* __restrict__ x,  const float* __restrict__ wq,
                         const float* __restrict__ wk, const float* __restrict__ wv,
                         const float* __restrict__ wo,
                         __bf16* __restrict__ xb,  __bf16* __restrict__ wqb,
                         __bf16* __restrict__ wkb, __bf16* __restrict__ wvb,
                         __bf16* __restrict__ wob)
{
  const float* in; __bf16* out; int n;
  switch (blockIdx.y) {
    case 0:  in = x;  out = xb;  n = MTOT * DMODEL;   break;
    case 1:  in = wq; out = wqb; n = DMODEL * DMODEL; break;
    case 2:  in = wk; out = wkb; n = DMODEL * DMODEL; break;
    case 3:  in = wv; out = wvb; n = DMODEL * DMODEL; break;
    default: in = wo; out = wob; n = DMODEL * DMODEL; break;
  }
  const int i = blockIdx.x * blockDim.x + threadIdx.x;
  const int stride = gridDim.x * blockDim.x;
  for (int idx = i; idx * 8 < n; idx += stride) {
    const float4 a = ((const float4*)in)[idx * 2];
    const float4 b = ((const float4*)in)[idx * 2 + 1];
    bf16x8 v = { (__bf16)a.x, (__bf16)a.y, (__bf16)a.z, (__bf16)a.w,
                 (__bf16)b.x, (__bf16)b.y, (__bf16)b.z, (__bf16)b.w };
    *(bf16x8*)(out + (size_t)idx * 8) = v;
  }
}

// ---------- shared 128x128 GEMM mainloop: acc = A[128,K] * W[128,K]^T ----------
__device__ __forceinline__ void gemm_tile_128(const __bf16* __restrict__ A,
                                              const __bf16* __restrict__ W,
                                              int bm, int bn, int Kd,
                                              f32x4 (&acc)[4][4])
{
  __shared__ __align__(16) __bf16 As[128 * 32];
  __shared__ __align__(16) __bf16 Bs[128 * 32];
  const int tid  = threadIdx.x;
  const int wave = tid >> 6, lane = tid & 63;
  const int wr = wave >> 1, wc = wave & 1;
  const int fr = lane & 15, fq = lane >> 4;
  const int c0 = tid, c1 = tid + 256;
  const __bf16* gA0 = A + (size_t)(bm * 128 + (c0 >> 2)) * Kd + (c0 & 3) * 8;
  const __bf16* gA1 = A + (size_t)(bm * 128 + (c1 >> 2)) * Kd + (c1 & 3) * 8;
  const __bf16* gB0 = W + (size_t)(bn * 128 + (c0 >> 2)) * Kd + (c0 & 3) * 8;
  const __bf16* gB1 = W + (size_t)(bn * 128 + (c1 >> 2)) * Kd + (c1 & 3) * 8;

  for (int k0 = 0; k0 < Kd; k0 += 32) {
    gload_lds16(gA0 + k0, As + c0 * 8);
    gload_lds16(gB0 + k0, Bs + c0 * 8);
    gload_lds16(gA1 + k0, As + c1 * 8);
    gload_lds16(gB1 + k0, Bs + c1 * 8);
    __syncthreads();
    bf16x8 a[4], b[4];
#pragma unroll
    for (int m = 0; m < 4; ++m)
      a[m] = *(const bf16x8*)(As + (wr * 64 + m * 16 + fr) * 32 + fq * 8);
#pragma unroll
    for (int n = 0; n < 4; ++n)
      b[n] = *(const bf16x8*)(Bs + (wc * 64 + n * 16 + fr) * 32 + fq * 8);
#pragma unroll
    for (int m = 0; m < 4; ++m)
#pragma unroll
      for (int n = 0; n < 4; ++n)
        acc[m][n] = __builtin_amdgcn_mfma_f32_16x16x32_bf16(a[m], b[n], acc[m][n], 0, 0, 0);
    __syncthreads();
  }
}

// ---------- QKV projections (z=0: Q*scale, z=1: K, z=2: VT = Wv * x^T) ----------
__global__ __launch_bounds__(256)
void gemm_qkv(const __bf16* __restrict__ xb,
              const __bf16* __restrict__ Wq, const __bf16* __restrict__ Wk,
              const __bf16* __restrict__ Wv,
              __bf16* __restrict__ Qo, __bf16* __restrict__ Ko, __bf16* __restrict__ VTo,
              float qscale)
{
  const int z = blockIdx.z;
  const __bf16* A; const __bf16* W; __bf16* Ob; float scale; int bm, bn, Nn;
  if (z == 2)      { A = Wv; W = xb; Ob = VTo; scale = 1.f;    bm = blockIdx.y; bn = blockIdx.x; Nn = MTOT;   }
  else if (z == 1) { A = xb; W = Wk; Ob = Ko;  scale = 1.f;    bm = blockIdx.x; bn = blockIdx.y; Nn = DMODEL; }
  else             { A = xb; W = Wq; Ob = Qo;  scale = qscale; bm = blockIdx.x; bn = blockIdx.y; Nn = DMODEL; }

  f32x4 acc[4][4] = {};
  gemm_tile_128(A, W, bm, bn, DMODEL, acc);

  const int lane = threadIdx.x & 63, wave = threadIdx.x >> 6;
  const int wr = wave >> 1, wc = wave & 1;
  const int fr = lane & 15, fq = lane >> 4;
#pragma unroll
  for (int m = 0; m < 4; ++m)
#pragma unroll
    for (int n = 0; n < 4; ++n) {
      const int col = bn * 128 + wc * 64 + n * 16 + fr;
#pragma unroll
      for (int j = 0; j < 4; ++j) {
        const int row = bm * 128 + wr * 64 + m * 16 + fq * 4 + j;
        Ob[(size_t)row * Nn + col] = (__bf16)(acc[m][n][j] * scale);
      }
    }
}

// ---------- output projection: out = ctx * Wo^T + b ----------
__global__ __launch_bounds__(256)
void gemm_out(const __bf16* __restrict__ A, const __bf16* __restrict__ W,
              float* __restrict__ OF, const float* __restrict__ bias)
{
  f32x4 acc[4][4] = {};
  gemm_tile_128(A, W, blockIdx.x, blockIdx.y, DMODEL, acc);

  const int lane = threadIdx.x & 63, wave = threadIdx.x >> 6;
  const int wr = wave >> 1, wc = wave & 1;
  const int fr = lane & 15, fq = lane >> 4;
#pragma unroll
  for (int m = 0; m < 4; ++m)
#pragma unroll
    for (int n = 0; n < 4; ++n) {
      const int col = blockIdx.y * 128 + wc * 64 + n * 16 + fr;
#pragma unroll
      for (int j = 0; j < 4; ++j) {
        const int row = blockIdx.x * 128 + wr * 64 + m * 16 + fq * 4 + j;
        OF[(size_t)row * DMODEL + col] = acc[m][n][j] + bias[col];
      }
    }
}

// ---------- flash attention ----------
// 1 wave = 1 workgroup (64 thr). Wave owns q-tile pair (j, 63-j): every wave
// runs exactly 33 kv-tile iterations (uniform duration, no stragglers).
// K / V^T tile loads are shared between the two q-streams.
// Swapped QK^T via 32x32x16 MFMA: S^T[kv][q], q = lane&31.
// C/D layout (m74/m101): col=lane&31, row=(r&3)+8*(r>>2)+4*(lane>>5).

// per-stream online softmax (base-2, T13 defer-max) + P-pack + PV
__device__ __forceinline__ void stream_step(f32x16& sv0, f32x16& sv1,
                                            float& m_run, float& l_run,
                                            f32x16& c0, f32x16& c1,
                                            const bf16x8 (&vt0)[4], const bf16x8 (&vt1)[4],
                                            int hi)
{
  float t8[8];
#pragma unroll
  for (int r = 0; r < 8; ++r)
    t8[r] = fmaxf(fmaxf(sv0[r], sv0[r + 8]), fmaxf(sv1[r], sv1[r + 8]));
#pragma unroll
  for (int r = 0; r < 4; ++r) t8[r] = fmaxf(t8[r], t8[r + 4]);
  float mx = fmaxf(fmaxf(t8[0], t8[1]), fmaxf(t8[2], t8[3]));
  mx = fmaxf(mx, __shfl_xor(mx, 32, 64));

  // T13 defer-max: skip rescale while per-tile max growth <= 8 (exp2 domain)
  if (!__all(mx <= m_run + 8.0f)) {
    const float mnew = fmaxf(m_run, mx);
    const float scl  = __builtin_amdgcn_exp2f(m_run - mnew);
    m_run = mnew;
    l_run *= scl;
#pragma unroll
    for (int r = 0; r < 16; ++r) { c0[r] *= scl; c1[r] *= scl; }
  }
#pragma unroll
  for (int r = 0; r < 16; ++r) {
    sv0[r] = __builtin_amdgcn_exp2f(sv0[r] - m_run);
    sv1[r] = __builtin_amdgcn_exp2f(sv1[r] - m_run);
  }
  float s8[8];
#pragma unroll
  for (int r = 0; r < 8; ++r)
    s8[r] = (sv0[r] + sv0[r + 8]) + (sv1[r] + sv1[r + 8]);
#pragma unroll
  for (int r = 0; r < 4; ++r) s8[r] += s8[r + 4];
  float sum = (s8[0] + s8[1]) + (s8[2] + s8[3]);
  sum += __shfl_xor(sum, 32, 64);
  l_run += sum;

  // pack P into PV B-fragments (half-exchange via shfl_xor 32)
  bf16x8 pf[4];
#pragma unroll
  for (int half = 0; half < 2; ++half) {
    const int r0 = half * 8;
    {
      unsigned pk01 = pkbf(sv0[r0 + 0], sv0[r0 + 1]);
      unsigned pk23 = pkbf(sv0[r0 + 2], sv0[r0 + 3]);
      unsigned pk45 = pkbf(sv0[r0 + 4], sv0[r0 + 5]);
      unsigned pk67 = pkbf(sv0[r0 + 6], sv0[r0 + 7]);
      unsigned x01 = (unsigned)__shfl_xor((int)pk01, 32, 64);
      unsigned x23 = (unsigned)__shfl_xor((int)pk23, 32, 64);
      unsigned x45 = (unsigned)__shfl_xor((int)pk45, 32, 64);
      unsigned x67 = (unsigned)__shfl_xor((int)pk67, 32, 64);
      u32x4 uw = { hi ? x45 : pk01, hi ? x67 : pk23,
                   hi ? pk45 : x01, hi ? pk67 : x23 };
      pf[half] = __builtin_bit_cast(bf16x8, uw);
    }
    {
      unsigned pk01 = pkbf(sv1[r0 + 0], sv1[r0 + 1]);
      unsigned pk23 = pkbf(sv1[r0 + 2], sv1[r0 + 3]);
      unsigned pk45 = pkbf(sv1[r0 + 4], sv1[r0 + 5]);
      unsigned pk67 = pkbf(sv1[r0 + 6], sv1[r0 + 7]);
      unsigned x01 = (unsigned)__shfl_xor((int)pk01, 32, 64);
      unsigned x23 = (unsigned)__shfl_xor((int)pk23, 32, 64);
      unsigned x45 = (unsigned)__shfl_xor((int)pk45, 32, 64);
      unsigned x67 = (unsigned)__shfl_xor((int)pk67, 32, 64);
      u32x4 uw = { hi ? x45 : pk01, hi ? x67 : pk23,
                   hi ? pk45 : x01, hi ? pk67 : x23 };
      pf[2 + half] = __builtin_bit_cast(bf16x8, uw);
    }
  }

  // PV: ctx^T[d][q] += V^T-frag * P-frag
#pragma unroll
  for (int kc = 0; kc < 4; ++kc)
    c0 = __builtin_amdgcn_mfma_f32_32x32x16_bf16(vt0[kc], pf[kc], c0, 0, 0, 0);
#pragma unroll
  for (int kc = 0; kc < 4; ++kc)
    c1 = __builtin_amdgcn_mfma_f32_32x32x16_bf16(vt1[kc], pf[kc], c1, 0, 0, 0);
}

__device__ __forceinline__ void mask_tile(f32x16& sv0, f32x16& sv1,
                                          int kv0, int q0, int ln, int hi)
{
  const int qg = q0 + ln;
#pragma unroll
  for (int r = 0; r < 16; ++r) {
    const int kvo = kv0 + (r & 3) + 8 * (r >> 2) + 4 * hi;
    if (kvo > qg)      sv0[r] = -1e30f;
    if (kvo + 32 > qg) sv1[r] = -1e30f;
  }
}

__global__ __launch_bounds__(64)
void attn_kernel(const __bf16* __restrict__ Qg, const __bf16* __restrict__ Kg,
                 const __bf16* __restrict__ VTg, __bf16* __restrict__ Og)
{
  const int lane = threadIdx.x & 63;
  const int ln  = lane & 31, hi = lane >> 5;
  const int j   = blockIdx.x;          // 0..31 -> q-tile pair (j, 63-j)
  const int bh  = blockIdx.y;          // 0..31
  const int b   = bh >> 4, h = bh & 15;

  const int q0L = j * 32;
  const int q0H = (63 - j) * 32;
  const int ntL = (q0L >> 6) + 1;
  const int ntH = (q0H >> 6) + 1;      // ntL + ntH == 33 for all j

  const __bf16* Kp  = Kg  + (size_t)b * SEQ * DMODEL + h * HDIM + hi * 8;
  const __bf16* Vp  = VTg + (size_t)(h * HDIM) * MTOT + (size_t)b * SEQ + hi * 8;
  const __bf16* QpL = Qg + ((size_t)b * SEQ + q0L + ln) * DMODEL + h * HDIM + hi * 8;
  const __bf16* QpH = Qg + ((size_t)b * SEQ + q0H + ln) * DMODEL + h * HDIM + hi * 8;
  __bf16*       OpL = Og + ((size_t)b * SEQ + q0L + ln) * DMODEL + h * HDIM;
  __bf16*       OpH = Og + ((size_t)b * SEQ + q0H + ln) * DMODEL + h * HDIM;

  // Q fragments (B-operand): q=ln, k = kc*16 + hi*8 + jj  (Q pre-scaled 0.125*log2e)
  bf16x8 qfL[4], qfH[4];
#pragma unroll
  for (int kc = 0; kc < 4; ++kc) {
    qfL[kc] = *(const bf16x8*)(QpL + kc * 16);
    qfH[kc] = *(const bf16x8*)(QpH + kc * 16);
  }

  f32x16 cL0 = {}, cL1 = {}, cH0 = {}, cH1 = {};
  float mL = -1e30f, lL = 0.f, mH = -1e30f, lH = 0.f;

  for (int t = 0; t < ntH; ++t) {
    const int kv0 = t * 64;
    const bool loAct = (t < ntL);

    // K fragments (A-operand), shared by both q-streams
    bf16x8 kA[4], kB[4];
#pragma unroll
    for (int kc = 0; kc < 4; ++kc) {
      kA[kc] = *(const bf16x8*)(Kp + (size_t)(kv0 + ln) * DMODEL + kc * 16);
      kB[kc] = *(const bf16x8*)(Kp + (size_t)(kv0 + 32 + ln) * DMODEL + kc * 16);
    }
    // V^T fragments (A-operand: d = db*32+ln, k = kv), shared by both streams
    bf16x8 vt0[4], vt1[4];
#pragma unroll
    for (int kc = 0; kc < 4; ++kc) {
      vt0[kc] = *(const bf16x8*)(Vp + (size_t)ln * MTOT + kv0 + kc * 16);
      vt1[kc] = *(const bf16x8*)(Vp + (size_t)(32 + ln) * MTOT + kv0 + kc * 16);
    }

    // S^T = K * Q^T for hi stream (always) and lo stream (while active)
    f32x16 sH0 = {}, sH1 = {};
#pragma unroll
    for (int kc = 0; kc < 4; ++kc) {
      sH0 = __builtin_amdgcn_mfma_f32_32x32x16_bf16(kA[kc], qfH[kc], sH0, 0, 0, 0);
      sH1 = __builtin_amdgcn_mfma_f32_32x32x16_bf16(kB[kc], qfH[kc], sH1, 0, 0, 0);
    }
    if (t == ntH - 1) mask_tile(sH0, sH1, kv0, q0H, ln, hi);
    stream_step(sH0, sH1, mH, lH, cH0, cH1, vt0, vt1, hi);

    if (loAct) {
      f32x16 sL0 = {}, sL1 = {};
#pragma unroll
      for (int kc = 0; kc < 4; ++kc) {
        sL0 = __builtin_amdgcn_mfma_f32_32x32x16_bf16(kA[kc], qfL[kc], sL0, 0, 0, 0);
        sL1 = __builtin_amdgcn_mfma_f32_32x32x16_bf16(kB[kc], qfL[kc], sL1, 0, 0, 0);
      }
      if (t == ntL - 1) mask_tile(sL0, sL1, kv0, q0L, ln, hi);
      stream_step(sL0, sL1, mL, lL, cL0, cL1, vt0, vt1, hi);
    }
  }

  // epilogue: divide by l, write bf16 (4 consecutive d per 8B store)
  const float invL = 1.0f / lL, invH = 1.0f / lH;
#pragma unroll
  for (int rq = 0; rq < 4; ++rq) {
    u32x2 w;
    w.x = pkbf(cL0[rq * 4 + 0] * invL, cL0[rq * 4 + 1] * invL);
    w.y = pkbf(cL0[rq * 4 + 2] * invL, cL0[rq * 4 + 3] * invL);
    *(u32x2*)(OpL + rq * 8 + hi * 4) = w;
    w.x = pkbf(cL1[rq * 4 + 0] * invL, cL1[rq * 4 + 1] * invL);
    w.y = pkbf(cL1[rq * 4 + 2] * invL, cL1[rq * 4 + 3] * invL);
    *(u32x2*)(OpL + 32 + rq * 8 + hi * 4) = w;
    w.x = pkbf(cH0[rq * 4 + 0] * invH, cH0[rq * 4 + 1] * invH);
    w.y = pkbf(cH0[rq * 4 + 2] * invH, cH0[rq * 4 + 3] * invH);
    *(u32x2*)(OpH + rq * 8 + hi * 4) = w;
    w.x = pkbf(cH1[rq * 4 + 0] * invH, cH1[rq * 4 + 1] * invH);
    w.y = pkbf(cH1[rq * 4 + 2] * invH, cH1[rq * 4 + 3] * invH);
    *(u32x2*)(OpH + 32 + rq * 8 + hi * 4) = w;
  }
}

// ---------- launch ----------
extern "C" void kernel_launch(void* const* d_in, const int* in_sizes, int n_in,
                              void* d_out, int out_size, void* d_ws, size_t ws_size,
                              hipStream_t stream) {
  (void)in_sizes; (void)n_in; (void)out_size; (void)ws_size;
  const float* x  = (const float*)d_in[0];
  const float* Wq = (const float*)d_in[1];
  const float* Wk = (const float*)d_in[2];
  const float* Wv = (const float*)d_in[3];
  const float* Wo = (const float*)d_in[4];
  const float* bo = (const float*)d_in[5];
  float* out = (float*)d_out;

  __bf16* ws  = (__bf16*)d_ws;
  __bf16* xb  = ws;                                   // 4M elems
  __bf16* Wqb = xb  + (size_t)MTOT * DMODEL;
  __bf16* Wkb = Wqb + (size_t)DMODEL * DMODEL;
  __bf16* Wvb = Wkb + (size_t)DMODEL * DMODEL;
  __bf16* Wob = Wvb + (size_t)DMODEL * DMODEL;
  __bf16* Qb  = Wob + (size_t)DMODEL * DMODEL;        // 4M
  __bf16* Kb  = Qb  + (size_t)MTOT * DMODEL;          // 4M
  __bf16* VTb = Kb  + (size_t)MTOT * DMODEL;          // 4M, layout [1024][4096]
  __bf16* ctxb = xb;  // reuse: x is dead after QKV projections

  cast_all<<<dim3(256, 5), 256, 0, stream>>>(x, Wq, Wk, Wv, Wo,
                                             xb, Wqb, Wkb, Wvb, Wob);

  // scale = 1/sqrt(64) * log2(e), folded into Q so softmax uses exp2
  const float qscale = 0.125f * 1.4426950408889634f;
  gemm_qkv<<<dim3(32, 8, 3), 256, 0, stream>>>(xb, Wqb, Wkb, Wvb, Qb, Kb, VTb, qscale);

  attn_kernel<<<dim3(32, 32), 64, 0, stream>>>(Qb, Kb, VTb, ctxb);

  gemm_out<<<dim3(32, 8), 256, 0, stream>>>(ctxb, Wob, out, bo);
}